// Round 8
// baseline (275.359 us; speedup 1.0000x reference)
//
#include <hip/hip_runtime.h>

typedef __attribute__((ext_vector_type(8))) short s16x8;
typedef __attribute__((ext_vector_type(4))) float f32x4;
typedef unsigned short u16;
typedef unsigned char u8;
typedef unsigned long long u64;

#define D_FEAT 128
#define TILE1 4096

__device__ __forceinline__ u16 f2bf(float f) {
    unsigned u = __builtin_bit_cast(unsigned, f);
    u = u + 0x7fffu + ((u >> 16) & 1u);   // RNE
    return (u16)(u >> 16);
}

// ---------------- fused prep: tobf16 | hist1 | emb | transpose (independent) ----------------
__global__ __launch_bounds__(256) void prep_kernel(
        const float4* __restrict__ X4, u16* __restrict__ xb, int n4, int nbA,
        const int* __restrict__ dst, int* __restrict__ ghist, int E, int nb1, int bins,
        const float* __restrict__ ee1_0, const float* __restrict__ ee2_0,
        const float* __restrict__ ee1_1, const float* __restrict__ ee2_1,
        float* __restrict__ emb,
        const float* __restrict__ W1_0, const float* __restrict__ W2_0,
        const float* __restrict__ W1_1, const float* __restrict__ W2_1,
        u16* __restrict__ wout) {
    __shared__ int h[256];
    const int t = threadIdx.x;
    int b = blockIdx.x;

    if (b < nbA) {                         // ---- x fp32 -> bf16
        int i = b * 256 + t;
        if (i < n4) {
            float4 v = X4[i];
            uint2 p;
            p.x = (unsigned)f2bf(v.x) | ((unsigned)f2bf(v.y) << 16);
            p.y = (unsigned)f2bf(v.z) | ((unsigned)f2bf(v.w) << 16);
            *(uint2*)(xb + (size_t)i * 4) = p;
        }
        return;
    }
    b -= nbA;
    if (b < nb1) {                         // ---- per-(bucket, block) histogram
        h[t] = 0;
        __syncthreads();
        const int base = b * TILE1;
        #pragma unroll
        for (int j = 0; j < TILE1 / 256; ++j) {
            int e = base + j * 256 + t;
            if (e < E) atomicAdd(&h[dst[e] >> 8], 1);
        }
        __syncthreads();
        if (t < bins) ghist[t * nb1 + b] = h[t];
        return;
    }
    b -= nb1;
    if (b < 18) {                          // ---- edge-code embedding table (2 layers x 18 x 128)
        int gi = b * 256 + t;              // 0..4607
        int layer = gi / 2304;
        int rem = gi - layer * 2304;
        int code = rem >> 7;
        int d = rem & 127;
        int a0 = code / 3, a1 = code - a0 * 3;
        const float* e1 = layer ? ee1_1 : ee1_0;
        const float* e2 = layer ? ee2_1 : ee2_0;
        emb[layer * 2304 + code * 128 + d] = e1[a0 * 128 + d] + e2[a1 * 128 + d];
        return;
    }
    b -= 18;
    {                                      // ---- weight transpose fp32 -> bf16 (4 mats x 128 blocks)
        int mat = b >> 7;
        const float* s = (mat == 0) ? W1_0 : (mat == 1) ? W2_0 : (mat == 2) ? W1_1 : W2_1;
        int K = (mat & 1) ? 256 : 128;
        int Nc = 384 - K;
        u16* d = wout + mat * 32768;
        int idx = (b & 127) * 256 + t;
        int n = idx / K, k = idx - n * K;
        d[idx] = f2bf(s[k * Nc + n]);
    }
}

// ---------------- scan1a: one block per bucket, scan per-block counts ----------------
__global__ __launch_bounds__(256) void scan1a_kernel(int* __restrict__ ghist,
                                                     int* __restrict__ btot, int nb1) {
    __shared__ int wt[4];
    const int t = threadIdx.x, lane = t & 63, wid = t >> 6;
    const int bin = blockIdx.x;
    const int v = (t < nb1) ? ghist[bin * nb1 + t] : 0;
    int s = v;
    #pragma unroll
    for (int off = 1; off < 64; off <<= 1) {
        int u = __shfl_up(s, off, 64);
        if (lane >= off) s += u;
    }
    if (lane == 63) wt[wid] = s;
    __syncthreads();
    int add = 0;
    #pragma unroll
    for (int w = 0; w < 4; ++w) add += (w < wid) ? wt[w] : 0;
    s += add;                                   // inclusive
    if (t < nb1) ghist[bin * nb1 + t] = s - v;  // exclusive, bucket-relative
    if (t == 255) btot[bin] = s;                // bucket total
}

// ---------------- scatter1: bucket-partitioned scatter; bucket bases from local btot scan ----
__global__ __launch_bounds__(256) void scatter1_kernel(const int* __restrict__ src,
                                                       const int* __restrict__ dst,
                                                       const int* __restrict__ eattr,
                                                       const int* __restrict__ ghist,
                                                       const int* __restrict__ btot,
                                                       u64* __restrict__ buf1,
                                                       int E, int nb1, int bins) {
    __shared__ int lofs[256];
    __shared__ int wt[4];
    const int t = threadIdx.x, lane = t & 63, wid = t >> 6;
    const int v = (t < bins) ? btot[t] : 0;
    int s = v;
    #pragma unroll
    for (int off = 1; off < 64; off <<= 1) {
        int u = __shfl_up(s, off, 64);
        if (lane >= off) s += u;
    }
    if (lane == 63) wt[wid] = s;
    __syncthreads();
    int add = 0;
    #pragma unroll
    for (int w = 0; w < 4; ++w) add += (w < wid) ? wt[w] : 0;
    s += add;
    if (t < bins) lofs[t] = (s - v) + ghist[t * nb1 + blockIdx.x];
    __syncthreads();

    const int base = blockIdx.x * TILE1;
    #pragma unroll
    for (int j = 0; j < TILE1 / 256; ++j) {
        int e = base + j * 256 + t;
        if (e < E) {
            int d = dst[e];
            int2 at = ((const int2*)eattr)[e];
            unsigned pay = (unsigned)src[e] | ((unsigned)(at.x * 3 + at.y) << 16);
            int pos = atomicAdd(&lofs[d >> 8], 1);
            buf1[pos] = ((u64)(unsigned)d << 32) | pay;
        }
    }
}

// ---------------- bucket2: counting sort + code histogram, 1024 threads/block ----------------
__global__ __launch_bounds__(1024) void bucket2_kernel(const u64* __restrict__ buf1,
                                                       const int* __restrict__ btot,
                                                       int* __restrict__ row_start,
                                                       unsigned* __restrict__ edges,
                                                       unsigned* __restrict__ countsw,
                                                       int N, int bins) {
    __shared__ int cnt[256];
    __shared__ int cur[256];
    __shared__ int wts[4];
    __shared__ unsigned ccnt[256 * 18];
    __shared__ int sb[2];
    const int t = threadIdx.x, lane = t & 63, wid = t >> 6;
    const int bin = blockIdx.x;

    int v0 = 0, s0 = 0;
    if (t < 256) {
        v0 = (t < bins) ? btot[t] : 0;
        s0 = v0;
        #pragma unroll
        for (int off = 1; off < 64; off <<= 1) {
            int u = __shfl_up(s0, off, 64);
            if (lane >= off) s0 += u;
        }
        if (lane == 63) wts[wid] = s0;
        cnt[t] = 0;
    }
    for (int i = t; i < 256 * 18; i += 1024) ccnt[i] = 0;
    __syncthreads();
    if (t < 256) {
        int add = 0;
        #pragma unroll
        for (int w = 0; w < 4; ++w) add += (w < wid) ? wts[w] : 0;
        s0 += add;
        if (t == bin) { sb[0] = s0 - v0; sb[1] = s0; }   // lo, hi
    }
    __syncthreads();
    const int lo = sb[0], hi = sb[1];

    for (int i = lo + t; i < hi; i += 1024)
        atomicAdd(&cnt[(int)(buf1[i] >> 32) & 255], 1);
    __syncthreads();

    int v1 = 0, s1 = 0;
    if (t < 256) {
        v1 = cnt[t];
        s1 = v1;
        #pragma unroll
        for (int off = 1; off < 64; off <<= 1) {
            int u = __shfl_up(s1, off, 64);
            if (lane >= off) s1 += u;
        }
        if (lane == 63) wts[wid] = s1;
    }
    __syncthreads();
    if (t < 256) {
        int add = 0;
        #pragma unroll
        for (int w = 0; w < 4; ++w) add += (w < wid) ? wts[w] : 0;
        s1 += add;
        const int g = bin * 256 + t;
        if (g < N) row_start[g + 1] = lo + s1;
        cur[t] = s1 - v1;
        if (bin == 0 && t == 0) row_start[0] = 0;
    }
    __syncthreads();

    for (int i = lo + t; i < hi; i += 1024) {
        u64 rec = buf1[i];
        const int local = (int)(rec >> 32) & 255;
        int loc = atomicAdd(&cur[local], 1);
        edges[lo + loc] = (unsigned)rec;
        atomicAdd(&ccnt[local * 18 + ((unsigned)rec >> 16)], 1);
    }
    __syncthreads();

    if (t < 256) {
        const int g = bin * 256 + t;
        if (g < N) {
            unsigned w[5] = {0, 0, 0, 0, 0};
            #pragma unroll
            for (int c = 0; c < 18; ++c)
                w[c >> 2] |= ccnt[t * 18 + c] << (8 * (c & 3));
            #pragma unroll
            for (int k = 0; k < 5; ++k)
                countsw[(size_t)g * 5 + k] = w[k];
        }
    }
}

// ---------------- aggregation: one wave per node, dwordx4 gathers (4 edges/load) ----------------
// Lane l reads 16B (8 bf16 dims, offset (l&15)*16B) of the row chosen by its quad
// (lane>>4): 16 lanes cover one 256B row, so ONE wave-load gathers FOUR edges.
// Row addresses come from 4 readlane-broadcast SGPRs + 3 cndmask selects.
// Finish: butterfly shfl_xor(16,32) reduce of 8 accs; emb-count epilogue distributed
// across quads (code = 4i+quad keeps cw[] statically indexed); lanes 0-15 store uint4.
__global__ __launch_bounds__(256) void aggregate_kernel(const u16* __restrict__ X,
                                                        const int* __restrict__ row_start,
                                                        const unsigned* __restrict__ edges,
                                                        const float* __restrict__ emb,
                                                        const unsigned* __restrict__ countsw,
                                                        u16* __restrict__ A, int N) {
    __shared__ float semb[18 * 128];
    for (int i = threadIdx.x; i < 18 * 128; i += 256) semb[i] = emb[i];
    __syncthreads();
    const int node = blockIdx.x * 4 + (threadIdx.x >> 6);
    const int lane = threadIdx.x & 63;
    if (node >= N) return;
    const int quad = lane >> 4;
    const int m16 = lane & 15;
    const bool b16 = (lane & 16) != 0;
    const bool b32 = (lane & 32) != 0;

    unsigned cw[5];
    #pragma unroll
    for (int k = 0; k < 5; ++k) cw[k] = countsw[(size_t)node * 5 + k];

    int s = __builtin_amdgcn_readfirstlane(row_start[node]);
    const int e = __builtin_amdgcn_readfirstlane(row_start[node + 1]);

    float acc[8];
    #pragma unroll
    for (int k = 0; k < 8; ++k) acc[k] = 0.f;

    while (s < e) {
        const int take = (e - s < 64) ? (e - s) : 64;             // wave-uniform
        unsigned pl = edges[s + (lane < take ? lane : 0)];        // 1 coalesced load
        #pragma unroll
        for (int g = 0; g < 16; ++g) {
            if (g * 4 < take) {                                   // uniform skip
                const unsigned w0 = __builtin_amdgcn_readlane(pl, g * 4 + 0) & 0xFFFFu;
                const unsigned w1 = __builtin_amdgcn_readlane(pl, g * 4 + 1) & 0xFFFFu;
                const unsigned w2 = __builtin_amdgcn_readlane(pl, g * 4 + 2) & 0xFFFFu;
                const unsigned w3 = __builtin_amdgcn_readlane(pl, g * 4 + 3) & 0xFFFFu;
                const unsigned r01 = b16 ? w1 : w0;
                const unsigned r23 = b16 ? w3 : w2;
                const unsigned row = b32 ? r23 : r01;
                const uint4 xv = *(const uint4*)(X + row * D_FEAT + m16 * 8);
                const float mv = (g * 4 + quad < take) ? 1.f : 0.f;
                acc[0] += mv * __builtin_bit_cast(float, xv.x << 16);
                acc[1] += mv * __builtin_bit_cast(float, xv.x & 0xFFFF0000u);
                acc[2] += mv * __builtin_bit_cast(float, xv.y << 16);
                acc[3] += mv * __builtin_bit_cast(float, xv.y & 0xFFFF0000u);
                acc[4] += mv * __builtin_bit_cast(float, xv.z << 16);
                acc[5] += mv * __builtin_bit_cast(float, xv.z & 0xFFFF0000u);
                acc[6] += mv * __builtin_bit_cast(float, xv.w << 16);
                acc[7] += mv * __builtin_bit_cast(float, xv.w & 0xFFFF0000u);
            }
        }
        s += take;
    }

    // emb-count epilogue, distributed: quad q handles codes {4i+q}, i=0..4 (<18).
    // cw word index = (4i+q)>>2 = i (static); byte = q.
    #pragma unroll
    for (int i = 0; i < 5; ++i) {
        const int code = 4 * i + quad;
        const bool valid = code < 18;
        const int codeC = valid ? code : 0;
        const float cf = valid ? (float)((cw[i] >> (8 * quad)) & 255u) : 0.f;
        const float* ep = semb + codeC * 128 + m16 * 8;
        const float4 e0 = *(const float4*)(ep);
        const float4 e1 = *(const float4*)(ep + 4);
        acc[0] += cf * e0.x;
        acc[1] += cf * e0.y;
        acc[2] += cf * e0.z;
        acc[3] += cf * e0.w;
        acc[4] += cf * e1.x;
        acc[5] += cf * e1.y;
        acc[6] += cf * e1.z;
        acc[7] += cf * e1.w;
    }

    // butterfly reduce across quads (lanes l, l+16, l+32, l+48)
    #pragma unroll
    for (int k = 0; k < 8; ++k) acc[k] += __shfl_xor(acc[k], 16, 64);
    #pragma unroll
    for (int k = 0; k < 8; ++k) acc[k] += __shfl_xor(acc[k], 32, 64);

    if (lane < 16) {
        uint4 o;
        o.x = (unsigned)f2bf(acc[0]) | ((unsigned)f2bf(acc[1]) << 16);
        o.y = (unsigned)f2bf(acc[2]) | ((unsigned)f2bf(acc[3]) << 16);
        o.z = (unsigned)f2bf(acc[4]) | ((unsigned)f2bf(acc[5]) << 16);
        o.w = (unsigned)f2bf(acc[6]) | ((unsigned)f2bf(acc[7]) << 16);
        *(uint4*)(A + (size_t)node * D_FEAT + lane * 8) = o;
    }
}

// ---------------- persistent-weight fused MLP ----------------
template <bool RELU2, bool OUTF32>
__global__ __launch_bounds__(256, 1) void mlp_kernel(const u16* __restrict__ A,
                                                     const u16* __restrict__ B1t,
                                                     const float* __restrict__ bias1,
                                                     const u16* __restrict__ B2t,
                                                     const float* __restrict__ bias2,
                                                     void* __restrict__ C, int M, int nt) {
    extern __shared__ __align__(16) u16 lds[];
    u16* w1 = lds;              // 32768 u16
    u16* w2 = lds + 32768;      // 32768 u16
    u16* hh = lds + 65536;      // 16384 u16, XOR-swizzled
    const int tid = threadIdx.x;
    const int wave = tid >> 6;
    const int lane = tid & 63;
    const int m16 = lane & 15;
    const int quad = lane >> 4;

    {
        const uint4* src1 = (const uint4*)B1t;
        const uint4* src2 = (const uint4*)B2t;
        #pragma unroll
        for (int i = 0; i < 16; ++i) {
            int s = i * 256 + tid;
            uint4 v = src1[s];
            int c = (((s >> 8) * 4 + ((s >> 2) & 3)) << 6) | ((s & 3) << 4) | ((s >> 4) & 15);
            *(uint4*)(w1 + c * 8) = v;
        }
        #pragma unroll
        for (int i = 0; i < 16; ++i) {
            int s = i * 256 + tid;
            uint4 v = src2[s];
            int c = (((s >> 9) * 8 + ((s >> 2) & 7)) << 6) | ((s & 3) << 4) | ((s >> 5) & 15);
            *(uint4*)(w2 + c * 8) = v;
        }
    }
    float b1v[16];
    #pragma unroll
    for (int t = 0; t < 16; ++t) b1v[t] = bias1[t * 16 + m16];
    float b2v[8];
    #pragma unroll
    for (int t = 0; t < 8; ++t) b2v[t] = bias2[t * 16 + m16];

    const int hbase = wave * 4096;

    int tile = blockIdx.x;
    s16x8 af[4];
    #pragma unroll
    for (int kb = 0; kb < 4; ++kb) af[kb] = s16x8{};
    if (tile < nt) {
        const int arow = tile * 64 + wave * 16 + m16;
        if (arow < M) {
            #pragma unroll
            for (int kb = 0; kb < 4; ++kb)
                af[kb] = *(const s16x8*)(A + (size_t)arow * 128 + kb * 32 + quad * 8);
        }
    }

    __syncthreads();

    for (; tile < nt; tile += 256) {
        const int row0 = tile * 64 + wave * 16;

        f32x4 acc[16];
        #pragma unroll
        for (int t = 0; t < 16; ++t) acc[t] = f32x4{0, 0, 0, 0};
        #pragma unroll
        for (int kb = 0; kb < 4; ++kb) {
            #pragma unroll
            for (int t = 0; t < 16; ++t) {
                s16x8 bf = *(const s16x8*)(w1 + (((((t << 2) | kb) << 6) | lane) * 8));
                acc[t] = __builtin_amdgcn_mfma_f32_16x16x32_bf16(af[kb], bf, acc[t], 0, 0, 0);
            }
        }

        const int ntile = tile + 256;
        s16x8 afn[4];
        #pragma unroll
        for (int kb = 0; kb < 4; ++kb) afn[kb] = s16x8{};
        if (ntile < nt) {
            const int arow = ntile * 64 + wave * 16 + m16;
            if (arow < M) {
                #pragma unroll
                for (int kb = 0; kb < 4; ++kb)
                    afn[kb] = *(const s16x8*)(A + (size_t)arow * 128 + kb * 32 + quad * 8);
            }
        }

        #pragma unroll
        for (int t = 0; t < 16; ++t) {
            const int col = t * 16 + m16;
            #pragma unroll
            for (int r = 0; r < 4; ++r) {
                const int row = quad * 4 + r;
                float v = acc[t][r] + b1v[t];
                v = v > 0.f ? v : 0.f;
                hh[(hbase + row * 256 + col) ^ ((row & 7) << 3)] = f2bf(v);
            }
        }
        __syncthreads();

        f32x4 acc2[8];
        #pragma unroll
        for (int t = 0; t < 8; ++t) acc2[t] = f32x4{0, 0, 0, 0};
        #pragma unroll
        for (int kb = 0; kb < 8; ++kb) {
            s16x8 haf = *(const s16x8*)(hh + ((hbase + m16 * 256 + kb * 32 + quad * 8) ^ ((m16 & 7) << 3)));
            #pragma unroll
            for (int t = 0; t < 8; ++t) {
                s16x8 bf = *(const s16x8*)(w2 + (((((t << 3) | kb) << 6) | lane) * 8));
                acc2[t] = __builtin_amdgcn_mfma_f32_16x16x32_bf16(haf, bf, acc2[t], 0, 0, 0);
            }
        }

        #pragma unroll
        for (int t = 0; t < 8; ++t) {
            const int col = t * 16 + m16;
            #pragma unroll
            for (int r = 0; r < 4; ++r) {
                const int row = row0 + quad * 4 + r;
                if (row < M) {
                    float v = acc2[t][r] + b2v[t];
                    if (RELU2) v = v > 0.f ? v : 0.f;
                    if (OUTF32) ((float*)C)[(size_t)row * 128 + col] = v;
                    else        ((u16*)C)[(size_t)row * 128 + col] = f2bf(v);
                }
            }
        }
        __syncthreads();

        #pragma unroll
        for (int kb = 0; kb < 4; ++kb) af[kb] = afn[kb];
    }
}

extern "C" void kernel_launch(void* const* d_in, const int* in_sizes, int n_in,
                              void* d_out, int out_size, void* d_ws, size_t ws_size,
                              hipStream_t stream) {
    const int N = in_sizes[0] / D_FEAT;     // 50000
    const int E = in_sizes[1] / 2;          // 800000

    const float* x    = (const float*)d_in[0];
    const int* eidx   = (const int*)d_in[1];
    const int* eattr  = (const int*)d_in[2];
    const float* ee1_0 = (const float*)d_in[3];
    const float* ee2_0 = (const float*)d_in[4];
    const float* W1_0  = (const float*)d_in[5];
    const float* b1_0  = (const float*)d_in[6];
    const float* W2_0  = (const float*)d_in[7];
    const float* b2_0  = (const float*)d_in[8];
    const float* ee1_1 = (const float*)d_in[9];
    const float* ee2_1 = (const float*)d_in[10];
    const float* W1_1  = (const float*)d_in[11];
    const float* b1_1  = (const float*)d_in[12];
    const float* W2_1  = (const float*)d_in[13];
    const float* b2_1  = (const float*)d_in[14];

    const int nb1  = (E + TILE1 - 1) / TILE1;     // 196
    const int bins = (N + 255) / 256;             // 196

    char* ws = (char*)d_ws;
    size_t off = 0;
    auto alloc = [&](size_t bytes) { size_t o = off; off = (off + bytes + 255) & ~(size_t)255; return o; };
    size_t o_rowstart = alloc((size_t)(N + 4) * 4);
    size_t o_edges    = alloc((size_t)E * 4);
    size_t o_ghist    = alloc((size_t)bins * nb1 * 4);
    size_t o_btot     = alloc((size_t)bins * 4);
    size_t o_counts   = alloc((size_t)N * 20);
    size_t o_emb      = alloc(2 * 18 * 128 * 4);
    size_t o_wt       = alloc(4 * 32768 * 2);
    size_t o_aa       = alloc((size_t)N * D_FEAT * 2);

    int*      row_start = (int*)(ws + o_rowstart);
    unsigned* edges     = (unsigned*)(ws + o_edges);
    int*      ghist     = (int*)(ws + o_ghist);
    int*      btot      = (int*)(ws + o_btot);
    unsigned* countsw   = (unsigned*)(ws + o_counts);
    float*    emb       = (float*)(ws + o_emb);
    u16*      W1t_0     = (u16*)(ws + o_wt);
    u16*      W2t_0     = W1t_0 + 32768;
    u16*      W1t_1     = W2t_0 + 32768;
    u16*      W2t_1     = W1t_1 + 32768;
    u16*      AA        = (u16*)(ws + o_aa);
    u64*      buf1      = (u64*)(ws + o_aa);      // aliases AA (dead before aggregate)

    u16* X2 = (u16*)d_out;
    u16* xb = (u16*)d_out + (size_t)N * D_FEAT;

    const int nt = (N + 63) / 64;                 // 782
    const int aggB = (N + 3) / 4;                 // 1 node/wave, 4 waves/block
    const int n4 = N * D_FEAT / 4;
    const int nbA = (n4 + 255) / 256;             // 6250
    const int LDS_MLP = 163840;

    static bool attr_done = false;
    if (!attr_done) {
        hipFuncSetAttribute((const void*)mlp_kernel<true, false>,
                            hipFuncAttributeMaxDynamicSharedMemorySize, LDS_MLP);
        hipFuncSetAttribute((const void*)mlp_kernel<false, true>,
                            hipFuncAttributeMaxDynamicSharedMemorySize, LDS_MLP);
        attr_done = true;
    }

    // 1) fused prep: tobf16 | hist1 | emb | transpose
    prep_kernel<<<nbA + nb1 + 18 + 512, 256, 0, stream>>>(
        (const float4*)x, xb, n4, nbA,
        eidx + E, ghist, E, nb1, bins,
        ee1_0, ee2_0, ee1_1, ee2_1, emb,
        W1_0, W2_0, W1_1, W2_1, W1t_0);

    // 2-4) CSR build
    scan1a_kernel<<<bins, 256, 0, stream>>>(ghist, btot, nb1);
    scatter1_kernel<<<nb1, 256, 0, stream>>>(eidx, eidx + E, eattr, ghist, btot, buf1, E, nb1, bins);
    bucket2_kernel<<<bins, 1024, 0, stream>>>(buf1, btot, row_start, edges, countsw, N, bins);

    // 5-6) layer 0
    aggregate_kernel<<<aggB, 256, 0, stream>>>(xb, row_start, edges, emb, countsw, AA, N);
    mlp_kernel<true, false><<<256, 256, LDS_MLP, stream>>>(AA, W1t_0, b1_0, W2t_0, b2_0, X2, N, nt);

    // 7-8) layer 1
    aggregate_kernel<<<aggB, 256, 0, stream>>>(X2, row_start, edges, emb + 18 * 128, countsw, AA, N);
    mlp_kernel<false, true><<<256, 256, LDS_MLP, stream>>>(AA, W1t_1, b1_1, W2t_1, b2_1, d_out, N, nt);
}

// Round 9
// 264.102 us; speedup vs baseline: 1.0426x; 1.0426x over previous
//
#include <hip/hip_runtime.h>

typedef __attribute__((ext_vector_type(8))) short s16x8;
typedef __attribute__((ext_vector_type(4))) float f32x4;
typedef unsigned short u16;
typedef unsigned char u8;
typedef unsigned long long u64;

#define D_FEAT 128
#define TILE1 4096

__device__ __forceinline__ u16 f2bf(float f) {
    unsigned u = __builtin_bit_cast(unsigned, f);
    u = u + 0x7fffu + ((u >> 16) & 1u);   // RNE
    return (u16)(u >> 16);
}

// ---------------- fused prep: tobf16 | hist1 | emb | transpose (independent) ----------------
__global__ __launch_bounds__(256) void prep_kernel(
        const float4* __restrict__ X4, u16* __restrict__ xb, int n4, int nbA,
        const int* __restrict__ dst, int* __restrict__ ghist, int E, int nb1, int bins,
        const float* __restrict__ ee1_0, const float* __restrict__ ee2_0,
        const float* __restrict__ ee1_1, const float* __restrict__ ee2_1,
        float* __restrict__ emb,
        const float* __restrict__ W1_0, const float* __restrict__ W2_0,
        const float* __restrict__ W1_1, const float* __restrict__ W2_1,
        u16* __restrict__ wout) {
    __shared__ int h[256];
    const int t = threadIdx.x;
    int b = blockIdx.x;

    if (b < nbA) {                         // ---- x fp32 -> bf16 (grid-stride, persistent)
        for (int i = b * 256 + t; i < n4; i += nbA * 256) {
            float4 v = X4[i];
            uint2 p;
            p.x = (unsigned)f2bf(v.x) | ((unsigned)f2bf(v.y) << 16);
            p.y = (unsigned)f2bf(v.z) | ((unsigned)f2bf(v.w) << 16);
            *(uint2*)(xb + (size_t)i * 4) = p;
        }
        return;
    }
    b -= nbA;
    if (b < nb1) {                         // ---- per-(bucket, block) histogram
        h[t] = 0;
        __syncthreads();
        const int base = b * TILE1;
        #pragma unroll
        for (int j = 0; j < TILE1 / 256; ++j) {
            int e = base + j * 256 + t;
            if (e < E) atomicAdd(&h[dst[e] >> 8], 1);
        }
        __syncthreads();
        if (t < bins) ghist[t * nb1 + b] = h[t];
        return;
    }
    b -= nb1;
    if (b < 18) {                          // ---- edge-code embedding table (2 layers x 18 x 128)
        int gi = b * 256 + t;              // 0..4607
        int layer = gi / 2304;
        int rem = gi - layer * 2304;
        int code = rem >> 7;
        int d = rem & 127;
        int a0 = code / 3, a1 = code - a0 * 3;
        const float* e1 = layer ? ee1_1 : ee1_0;
        const float* e2 = layer ? ee2_1 : ee2_0;
        emb[layer * 2304 + code * 128 + d] = e1[a0 * 128 + d] + e2[a1 * 128 + d];
        return;
    }
    b -= 18;
    {                                      // ---- weight transpose fp32 -> bf16 (4 mats x 128 blocks)
        int mat = b >> 7;
        const float* s = (mat == 0) ? W1_0 : (mat == 1) ? W2_0 : (mat == 2) ? W1_1 : W2_1;
        int K = (mat & 1) ? 256 : 128;
        int Nc = 384 - K;
        u16* d = wout + mat * 32768;
        int idx = (b & 127) * 256 + t;
        int n = idx / K, k = idx - n * K;
        d[idx] = f2bf(s[k * Nc + n]);
    }
}

// ---------------- scan1a: one block per bucket, scan per-block counts ----------------
__global__ __launch_bounds__(256) void scan1a_kernel(int* __restrict__ ghist,
                                                     int* __restrict__ btot, int nb1) {
    __shared__ int wt[4];
    const int t = threadIdx.x, lane = t & 63, wid = t >> 6;
    const int bin = blockIdx.x;
    const int v = (t < nb1) ? ghist[bin * nb1 + t] : 0;
    int s = v;
    #pragma unroll
    for (int off = 1; off < 64; off <<= 1) {
        int u = __shfl_up(s, off, 64);
        if (lane >= off) s += u;
    }
    if (lane == 63) wt[wid] = s;
    __syncthreads();
    int add = 0;
    #pragma unroll
    for (int w = 0; w < 4; ++w) add += (w < wid) ? wt[w] : 0;
    s += add;                                   // inclusive
    if (t < nb1) ghist[bin * nb1 + t] = s - v;  // exclusive, bucket-relative
    if (t == 255) btot[bin] = s;                // bucket total
}

// ---------------- scatter1: bucket-partitioned scatter; bucket bases from local btot scan ----
__global__ __launch_bounds__(256) void scatter1_kernel(const int* __restrict__ src,
                                                       const int* __restrict__ dst,
                                                       const int* __restrict__ eattr,
                                                       const int* __restrict__ ghist,
                                                       const int* __restrict__ btot,
                                                       u64* __restrict__ buf1,
                                                       int E, int nb1, int bins) {
    __shared__ int lofs[256];
    __shared__ int wt[4];
    const int t = threadIdx.x, lane = t & 63, wid = t >> 6;
    const int v = (t < bins) ? btot[t] : 0;
    int s = v;
    #pragma unroll
    for (int off = 1; off < 64; off <<= 1) {
        int u = __shfl_up(s, off, 64);
        if (lane >= off) s += u;
    }
    if (lane == 63) wt[wid] = s;
    __syncthreads();
    int add = 0;
    #pragma unroll
    for (int w = 0; w < 4; ++w) add += (w < wid) ? wt[w] : 0;
    s += add;
    if (t < bins) lofs[t] = (s - v) + ghist[t * nb1 + blockIdx.x];
    __syncthreads();

    const int base = blockIdx.x * TILE1;
    #pragma unroll
    for (int j = 0; j < TILE1 / 256; ++j) {
        int e = base + j * 256 + t;
        if (e < E) {
            int d = dst[e];
            int2 at = ((const int2*)eattr)[e];
            unsigned pay = (unsigned)src[e] | ((unsigned)(at.x * 3 + at.y) << 16);
            int pos = atomicAdd(&lofs[d >> 8], 1);
            buf1[pos] = ((u64)(unsigned)d << 32) | pay;
        }
    }
}

// ---------------- bucket2: counting sort + code histogram, 1024 threads/block ----------------
__global__ __launch_bounds__(1024) void bucket2_kernel(const u64* __restrict__ buf1,
                                                       const int* __restrict__ btot,
                                                       int* __restrict__ row_start,
                                                       unsigned* __restrict__ edges,
                                                       unsigned* __restrict__ countsw,
                                                       int N, int bins) {
    __shared__ int cnt[256];
    __shared__ int cur[256];
    __shared__ int wts[4];
    __shared__ unsigned ccnt[256 * 18];
    __shared__ int sb[2];
    const int t = threadIdx.x, lane = t & 63, wid = t >> 6;
    const int bin = blockIdx.x;

    int v0 = 0, s0 = 0;
    if (t < 256) {
        v0 = (t < bins) ? btot[t] : 0;
        s0 = v0;
        #pragma unroll
        for (int off = 1; off < 64; off <<= 1) {
            int u = __shfl_up(s0, off, 64);
            if (lane >= off) s0 += u;
        }
        if (lane == 63) wts[wid] = s0;
        cnt[t] = 0;
    }
    for (int i = t; i < 256 * 18; i += 1024) ccnt[i] = 0;
    __syncthreads();
    if (t < 256) {
        int add = 0;
        #pragma unroll
        for (int w = 0; w < 4; ++w) add += (w < wid) ? wts[w] : 0;
        s0 += add;
        if (t == bin) { sb[0] = s0 - v0; sb[1] = s0; }   // lo, hi
    }
    __syncthreads();
    const int lo = sb[0], hi = sb[1];

    for (int i = lo + t; i < hi; i += 1024)
        atomicAdd(&cnt[(int)(buf1[i] >> 32) & 255], 1);
    __syncthreads();

    int v1 = 0, s1 = 0;
    if (t < 256) {
        v1 = cnt[t];
        s1 = v1;
        #pragma unroll
        for (int off = 1; off < 64; off <<= 1) {
            int u = __shfl_up(s1, off, 64);
            if (lane >= off) s1 += u;
        }
        if (lane == 63) wts[wid] = s1;
    }
    __syncthreads();
    if (t < 256) {
        int add = 0;
        #pragma unroll
        for (int w = 0; w < 4; ++w) add += (w < wid) ? wts[w] : 0;
        s1 += add;
        const int g = bin * 256 + t;
        if (g < N) row_start[g + 1] = lo + s1;
        cur[t] = s1 - v1;
        if (bin == 0 && t == 0) row_start[0] = 0;
    }
    __syncthreads();

    for (int i = lo + t; i < hi; i += 1024) {
        u64 rec = buf1[i];
        const int local = (int)(rec >> 32) & 255;
        int loc = atomicAdd(&cur[local], 1);
        edges[lo + loc] = (unsigned)rec;
        atomicAdd(&ccnt[local * 18 + ((unsigned)rec >> 16)], 1);
    }
    __syncthreads();

    if (t < 256) {
        const int g = bin * 256 + t;
        if (g < N) {
            unsigned w[5] = {0, 0, 0, 0, 0};
            #pragma unroll
            for (int c = 0; c < 18; ++c)
                w[c >> 2] |= ccnt[t * 18 + c] << (8 * (c & 3));
            #pragma unroll
            for (int k = 0; k < 5; ++k)
                countsw[(size_t)g * 5 + k] = w[k];
        }
    }
}

// ---------------- aggregation: persistent, one wave per node per iteration ----------------
// semb staged ONCE per block (2048 blocks, 8/CU); each wave grid-strides over ~6 nodes.
// Core loop = proven r5 structure: readlane-broadcast gathers, ~4 VALU/edge,
// edge-embedding folded into per-node count epilogue.
__global__ __launch_bounds__(256) void aggregate_kernel(const u16* __restrict__ X,
                                                        const int* __restrict__ row_start,
                                                        const unsigned* __restrict__ edges,
                                                        const float* __restrict__ emb,
                                                        const unsigned* __restrict__ countsw,
                                                        u16* __restrict__ A, int N) {
    __shared__ float semb[18 * 128];
    for (int i = threadIdx.x; i < 18 * 128; i += 256) semb[i] = emb[i];
    __syncthreads();
    const int lane = threadIdx.x & 63;
    const int wstart = blockIdx.x * 4 + (threadIdx.x >> 6);
    const int wstride = gridDim.x * 4;
    const float2* sem2 = (const float2*)semb;

    for (int node = wstart; node < N; node += wstride) {
        unsigned cw[5];
        #pragma unroll
        for (int k = 0; k < 5; ++k) cw[k] = countsw[(size_t)node * 5 + k];

        int s = __builtin_amdgcn_readfirstlane(row_start[node]);
        const int e = __builtin_amdgcn_readfirstlane(row_start[node + 1]);
        float a0 = 0.f, a1 = 0.f;

        while (s < e) {
            const int take = (e - s < 64) ? (e - s) : 64;             // wave-uniform
            unsigned pl = edges[s + (lane < take ? lane : 0)];        // 1 coalesced load
            #pragma unroll
            for (int c = 0; c < 4; ++c) {
                const int cb = c * 16;
                if (cb < take) {                                      // uniform branch
                    unsigned ps[16];
                    unsigned xv[16];
                    #pragma unroll
                    for (int j = 0; j < 16; ++j)
                        ps[j] = __builtin_amdgcn_readlane(pl, cb + j);  // SGPR broadcast
                    #pragma unroll
                    for (int j = 0; j < 16; ++j)
                        xv[j] = *(const unsigned*)(X + (ps[j] & 0xFFFFu) * D_FEAT + lane * 2);
                    #pragma unroll
                    for (int j = 0; j < 16; ++j) {
                        const float m = (cb + j < take) ? 1.f : 0.f;  // uniform mask
                        a0 += m * __builtin_bit_cast(float, xv[j] << 16);
                        a1 += m * __builtin_bit_cast(float, xv[j] & 0xFFFF0000u);
                    }
                }
            }
            s += take;
        }

        // epilogue: + sum_c count_c * emb[c][dim]
        #pragma unroll
        for (int w = 0; w < 5; ++w) {
            #pragma unroll
            for (int b = 0; b < 4; ++b) {
                const int code = w * 4 + b;
                if (code < 18) {
                    const float cf = (float)((cw[w] >> (8 * b)) & 255u);
                    float2 ev = sem2[code * 64 + lane];
                    a0 += cf * ev.x;
                    a1 += cf * ev.y;
                }
            }
        }

        unsigned outp = (unsigned)f2bf(a0) | ((unsigned)f2bf(a1) << 16);
        *(unsigned*)(A + (size_t)node * D_FEAT + lane * 2) = outp;
    }
}

// ---------------- persistent-weight fused MLP ----------------
template <bool RELU2, bool OUTF32>
__global__ __launch_bounds__(256, 1) void mlp_kernel(const u16* __restrict__ A,
                                                     const u16* __restrict__ B1t,
                                                     const float* __restrict__ bias1,
                                                     const u16* __restrict__ B2t,
                                                     const float* __restrict__ bias2,
                                                     void* __restrict__ C, int M, int nt) {
    extern __shared__ __align__(16) u16 lds[];
    u16* w1 = lds;              // 32768 u16
    u16* w2 = lds + 32768;      // 32768 u16
    u16* hh = lds + 65536;      // 16384 u16, XOR-swizzled
    const int tid = threadIdx.x;
    const int wave = tid >> 6;
    const int lane = tid & 63;
    const int m16 = lane & 15;
    const int quad = lane >> 4;

    {
        const uint4* src1 = (const uint4*)B1t;
        const uint4* src2 = (const uint4*)B2t;
        #pragma unroll
        for (int i = 0; i < 16; ++i) {
            int s = i * 256 + tid;
            uint4 v = src1[s];
            int c = (((s >> 8) * 4 + ((s >> 2) & 3)) << 6) | ((s & 3) << 4) | ((s >> 4) & 15);
            *(uint4*)(w1 + c * 8) = v;
        }
        #pragma unroll
        for (int i = 0; i < 16; ++i) {
            int s = i * 256 + tid;
            uint4 v = src2[s];
            int c = (((s >> 9) * 8 + ((s >> 2) & 7)) << 6) | ((s & 3) << 4) | ((s >> 5) & 15);
            *(uint4*)(w2 + c * 8) = v;
        }
    }
    float b1v[16];
    #pragma unroll
    for (int t = 0; t < 16; ++t) b1v[t] = bias1[t * 16 + m16];
    float b2v[8];
    #pragma unroll
    for (int t = 0; t < 8; ++t) b2v[t] = bias2[t * 16 + m16];

    const int hbase = wave * 4096;

    int tile = blockIdx.x;
    s16x8 af[4];
    #pragma unroll
    for (int kb = 0; kb < 4; ++kb) af[kb] = s16x8{};
    if (tile < nt) {
        const int arow = tile * 64 + wave * 16 + m16;
        if (arow < M) {
            #pragma unroll
            for (int kb = 0; kb < 4; ++kb)
                af[kb] = *(const s16x8*)(A + (size_t)arow * 128 + kb * 32 + quad * 8);
        }
    }

    __syncthreads();

    for (; tile < nt; tile += 256) {
        const int row0 = tile * 64 + wave * 16;

        f32x4 acc[16];
        #pragma unroll
        for (int t = 0; t < 16; ++t) acc[t] = f32x4{0, 0, 0, 0};
        #pragma unroll
        for (int kb = 0; kb < 4; ++kb) {
            #pragma unroll
            for (int t = 0; t < 16; ++t) {
                s16x8 bf = *(const s16x8*)(w1 + (((((t << 2) | kb) << 6) | lane) * 8));
                acc[t] = __builtin_amdgcn_mfma_f32_16x16x32_bf16(af[kb], bf, acc[t], 0, 0, 0);
            }
        }

        const int ntile = tile + 256;
        s16x8 afn[4];
        #pragma unroll
        for (int kb = 0; kb < 4; ++kb) afn[kb] = s16x8{};
        if (ntile < nt) {
            const int arow = ntile * 64 + wave * 16 + m16;
            if (arow < M) {
                #pragma unroll
                for (int kb = 0; kb < 4; ++kb)
                    afn[kb] = *(const s16x8*)(A + (size_t)arow * 128 + kb * 32 + quad * 8);
            }
        }

        #pragma unroll
        for (int t = 0; t < 16; ++t) {
            const int col = t * 16 + m16;
            #pragma unroll
            for (int r = 0; r < 4; ++r) {
                const int row = quad * 4 + r;
                float v = acc[t][r] + b1v[t];
                v = v > 0.f ? v : 0.f;
                hh[(hbase + row * 256 + col) ^ ((row & 7) << 3)] = f2bf(v);
            }
        }
        __syncthreads();

        f32x4 acc2[8];
        #pragma unroll
        for (int t = 0; t < 8; ++t) acc2[t] = f32x4{0, 0, 0, 0};
        #pragma unroll
        for (int kb = 0; kb < 8; ++kb) {
            s16x8 haf = *(const s16x8*)(hh + ((hbase + m16 * 256 + kb * 32 + quad * 8) ^ ((m16 & 7) << 3)));
            #pragma unroll
            for (int t = 0; t < 8; ++t) {
                s16x8 bf = *(const s16x8*)(w2 + (((((t << 3) | kb) << 6) | lane) * 8));
                acc2[t] = __builtin_amdgcn_mfma_f32_16x16x32_bf16(haf, bf, acc2[t], 0, 0, 0);
            }
        }

        #pragma unroll
        for (int t = 0; t < 8; ++t) {
            const int col = t * 16 + m16;
            #pragma unroll
            for (int r = 0; r < 4; ++r) {
                const int row = row0 + quad * 4 + r;
                if (row < M) {
                    float v = acc2[t][r] + b2v[t];
                    if (RELU2) v = v > 0.f ? v : 0.f;
                    if (OUTF32) ((float*)C)[(size_t)row * 128 + col] = v;
                    else        ((u16*)C)[(size_t)row * 128 + col] = f2bf(v);
                }
            }
        }
        __syncthreads();

        #pragma unroll
        for (int kb = 0; kb < 4; ++kb) af[kb] = afn[kb];
    }
}

extern "C" void kernel_launch(void* const* d_in, const int* in_sizes, int n_in,
                              void* d_out, int out_size, void* d_ws, size_t ws_size,
                              hipStream_t stream) {
    const int N = in_sizes[0] / D_FEAT;     // 50000
    const int E = in_sizes[1] / 2;          // 800000

    const float* x    = (const float*)d_in[0];
    const int* eidx   = (const int*)d_in[1];
    const int* eattr  = (const int*)d_in[2];
    const float* ee1_0 = (const float*)d_in[3];
    const float* ee2_0 = (const float*)d_in[4];
    const float* W1_0  = (const float*)d_in[5];
    const float* b1_0  = (const float*)d_in[6];
    const float* W2_0  = (const float*)d_in[7];
    const float* b2_0  = (const float*)d_in[8];
    const float* ee1_1 = (const float*)d_in[9];
    const float* ee2_1 = (const float*)d_in[10];
    const float* W1_1  = (const float*)d_in[11];
    const float* b1_1  = (const float*)d_in[12];
    const float* W2_1  = (const float*)d_in[13];
    const float* b2_1  = (const float*)d_in[14];

    const int nb1  = (E + TILE1 - 1) / TILE1;     // 196
    const int bins = (N + 255) / 256;             // 196

    char* ws = (char*)d_ws;
    size_t off = 0;
    auto alloc = [&](size_t bytes) { size_t o = off; off = (off + bytes + 255) & ~(size_t)255; return o; };
    size_t o_rowstart = alloc((size_t)(N + 4) * 4);
    size_t o_edges    = alloc((size_t)E * 4);
    size_t o_ghist    = alloc((size_t)bins * nb1 * 4);
    size_t o_btot     = alloc((size_t)bins * 4);
    size_t o_counts   = alloc((size_t)N * 20);
    size_t o_emb      = alloc(2 * 18 * 128 * 4);
    size_t o_wt       = alloc(4 * 32768 * 2);
    size_t o_aa       = alloc((size_t)N * D_FEAT * 2);

    int*      row_start = (int*)(ws + o_rowstart);
    unsigned* edges     = (unsigned*)(ws + o_edges);
    int*      ghist     = (int*)(ws + o_ghist);
    int*      btot      = (int*)(ws + o_btot);
    unsigned* countsw   = (unsigned*)(ws + o_counts);
    float*    emb       = (float*)(ws + o_emb);
    u16*      W1t_0     = (u16*)(ws + o_wt);
    u16*      W2t_0     = W1t_0 + 32768;
    u16*      W1t_1     = W2t_0 + 32768;
    u16*      W2t_1     = W1t_1 + 32768;
    u16*      AA        = (u16*)(ws + o_aa);
    u64*      buf1      = (u64*)(ws + o_aa);      // aliases AA (dead before aggregate)

    u16* X2 = (u16*)d_out;
    u16* xb = (u16*)d_out + (size_t)N * D_FEAT;

    const int nt = (N + 63) / 64;                 // 782
    const int n4 = N * D_FEAT / 4;
    const int nbA = 1024;                         // persistent tobf16 blocks
    const int aggB = 2048;                        // persistent aggregate blocks (8/CU)
    const int LDS_MLP = 163840;

    static bool attr_done = false;
    if (!attr_done) {
        hipFuncSetAttribute((const void*)mlp_kernel<true, false>,
                            hipFuncAttributeMaxDynamicSharedMemorySize, LDS_MLP);
        hipFuncSetAttribute((const void*)mlp_kernel<false, true>,
                            hipFuncAttributeMaxDynamicSharedMemorySize, LDS_MLP);
        attr_done = true;
    }

    // 1) fused prep: tobf16 | hist1 | emb | transpose
    prep_kernel<<<nbA + nb1 + 18 + 512, 256, 0, stream>>>(
        (const float4*)x, xb, n4, nbA,
        eidx + E, ghist, E, nb1, bins,
        ee1_0, ee2_0, ee1_1, ee2_1, emb,
        W1_0, W2_0, W1_1, W2_1, W1t_0);

    // 2-4) CSR build
    scan1a_kernel<<<bins, 256, 0, stream>>>(ghist, btot, nb1);
    scatter1_kernel<<<nb1, 256, 0, stream>>>(eidx, eidx + E, eattr, ghist, btot, buf1, E, nb1, bins);
    bucket2_kernel<<<bins, 1024, 0, stream>>>(buf1, btot, row_start, edges, countsw, N, bins);

    // 5-6) layer 0
    aggregate_kernel<<<aggB, 256, 0, stream>>>(xb, row_start, edges, emb, countsw, AA, N);
    mlp_kernel<true, false><<<256, 256, LDS_MLP, stream>>>(AA, W1t_0, b1_0, W2t_0, b2_0, X2, N, nt);

    // 7-8) layer 1
    aggregate_kernel<<<aggB, 256, 0, stream>>>(X2, row_start, edges, emb + 18 * 128, countsw, AA, N);
    mlp_kernel<false, true><<<256, 256, LDS_MLP, stream>>>(AA, W1t_1, b1_1, W2t_1, b2_1, d_out, N, nt);
}

// Round 10
// 253.679 us; speedup vs baseline: 1.0855x; 1.0411x over previous
//
#include <hip/hip_runtime.h>

typedef __attribute__((ext_vector_type(8))) short s16x8;
typedef __attribute__((ext_vector_type(4))) float f32x4;
typedef unsigned short u16;
typedef unsigned char u8;
typedef unsigned long long u64;

#define D_FEAT 128
#define TILE1 4096

__device__ __forceinline__ u16 f2bf(float f) {
    unsigned u = __builtin_bit_cast(unsigned, f);
    u = u + 0x7fffu + ((u >> 16) & 1u);   // RNE
    return (u16)(u >> 16);
}

// ---------------- fused prep: tobf16 | hist1 | emb | frag-transpose ----------------
// Weight buffers are written in MFMA FRAGMENT ORDER:
//   F1[((t*4+kb)*64+lane)*8+j]  = bf16(W1[k][n])  n=t*16+(lane&15), k=kb*32+(lane>>4)*8+j
//   F2[((t*8+kb)*64+lane)*8+j]  = bf16(W2[k][n])  (same decode, 8 k-frags)
// so the MLP can load per-wave weight slices straight into VGPRs with b128 loads.
__global__ __launch_bounds__(256) void prep_kernel(
        const float4* __restrict__ X4, u16* __restrict__ xb, int n4, int nbA,
        const int* __restrict__ dst, int* __restrict__ ghist, int E, int nb1, int bins,
        const float* __restrict__ ee1_0, const float* __restrict__ ee2_0,
        const float* __restrict__ ee1_1, const float* __restrict__ ee2_1,
        float* __restrict__ emb,
        const float* __restrict__ W1_0, const float* __restrict__ W2_0,
        const float* __restrict__ W1_1, const float* __restrict__ W2_1,
        u16* __restrict__ wout) {
    __shared__ int h[256];
    const int t = threadIdx.x;
    int b = blockIdx.x;

    if (b < nbA) {                         // ---- x fp32 -> bf16 (grid-stride)
        for (int i = b * 256 + t; i < n4; i += nbA * 256) {
            float4 v = X4[i];
            uint2 p;
            p.x = (unsigned)f2bf(v.x) | ((unsigned)f2bf(v.y) << 16);
            p.y = (unsigned)f2bf(v.z) | ((unsigned)f2bf(v.w) << 16);
            *(uint2*)(xb + (size_t)i * 4) = p;
        }
        return;
    }
    b -= nbA;
    if (b < nb1) {                         // ---- per-(bucket, block) histogram
        h[t] = 0;
        __syncthreads();
        const int base = b * TILE1;
        #pragma unroll
        for (int j = 0; j < TILE1 / 256; ++j) {
            int e = base + j * 256 + t;
            if (e < E) atomicAdd(&h[dst[e] >> 8], 1);
        }
        __syncthreads();
        if (t < bins) ghist[t * nb1 + b] = h[t];
        return;
    }
    b -= nb1;
    if (b < 18) {                          // ---- edge-code embedding table
        int gi = b * 256 + t;
        int layer = gi / 2304;
        int rem = gi - layer * 2304;
        int code = rem >> 7;
        int d = rem & 127;
        int a0 = code / 3, a1 = code - a0 * 3;
        const float* e1 = layer ? ee1_1 : ee1_0;
        const float* e2 = layer ? ee2_1 : ee2_0;
        emb[layer * 2304 + code * 128 + d] = e1[a0 * 128 + d] + e2[a1 * 128 + d];
        return;
    }
    b -= 18;
    {                                      // ---- weight frag-transpose (4 mats x 128 blocks)
        int mat = b >> 7;
        const float* s = (mat == 0) ? W1_0 : (mat == 1) ? W2_0 : (mat == 2) ? W1_1 : W2_1;
        u16* d = wout + mat * 32768;
        int o = (b & 127) * 256 + t;       // 0..32767
        int n, k;
        if (mat & 1) {                     // W2: [256][128], 8 k-frags
            const int tt = o >> 12, kb = (o >> 9) & 7, lane = (o >> 3) & 63, j = o & 7;
            n = tt * 16 + (lane & 15);
            k = kb * 32 + (lane >> 4) * 8 + j;
            d[o] = f2bf(s[k * 128 + n]);
        } else {                           // W1: [128][256], 4 k-frags
            const int tt = o >> 11, kb = (o >> 9) & 3, lane = (o >> 3) & 63, j = o & 7;
            n = tt * 16 + (lane & 15);
            k = kb * 32 + (lane >> 4) * 8 + j;
            d[o] = f2bf(s[k * 256 + n]);
        }
    }
}

// ---------------- scan1a: one block per bucket, scan per-block counts ----------------
__global__ __launch_bounds__(256) void scan1a_kernel(int* __restrict__ ghist,
                                                     int* __restrict__ btot, int nb1) {
    __shared__ int wt[4];
    const int t = threadIdx.x, lane = t & 63, wid = t >> 6;
    const int bin = blockIdx.x;
    const int v = (t < nb1) ? ghist[bin * nb1 + t] : 0;
    int s = v;
    #pragma unroll
    for (int off = 1; off < 64; off <<= 1) {
        int u = __shfl_up(s, off, 64);
        if (lane >= off) s += u;
    }
    if (lane == 63) wt[wid] = s;
    __syncthreads();
    int add = 0;
    #pragma unroll
    for (int w = 0; w < 4; ++w) add += (w < wid) ? wt[w] : 0;
    s += add;                                   // inclusive
    if (t < nb1) ghist[bin * nb1 + t] = s - v;  // exclusive, bucket-relative
    if (t == 255) btot[bin] = s;                // bucket total
}

// ---------------- scatter1 ----------------
__global__ __launch_bounds__(256) void scatter1_kernel(const int* __restrict__ src,
                                                       const int* __restrict__ dst,
                                                       const int* __restrict__ eattr,
                                                       const int* __restrict__ ghist,
                                                       const int* __restrict__ btot,
                                                       u64* __restrict__ buf1,
                                                       int E, int nb1, int bins) {
    __shared__ int lofs[256];
    __shared__ int wt[4];
    const int t = threadIdx.x, lane = t & 63, wid = t >> 6;
    const int v = (t < bins) ? btot[t] : 0;
    int s = v;
    #pragma unroll
    for (int off = 1; off < 64; off <<= 1) {
        int u = __shfl_up(s, off, 64);
        if (lane >= off) s += u;
    }
    if (lane == 63) wt[wid] = s;
    __syncthreads();
    int add = 0;
    #pragma unroll
    for (int w = 0; w < 4; ++w) add += (w < wid) ? wt[w] : 0;
    s += add;
    if (t < bins) lofs[t] = (s - v) + ghist[t * nb1 + blockIdx.x];
    __syncthreads();

    const int base = blockIdx.x * TILE1;
    #pragma unroll
    for (int j = 0; j < TILE1 / 256; ++j) {
        int e = base + j * 256 + t;
        if (e < E) {
            int d = dst[e];
            int2 at = ((const int2*)eattr)[e];
            unsigned pay = (unsigned)src[e] | ((unsigned)(at.x * 3 + at.y) << 16);
            int pos = atomicAdd(&lofs[d >> 8], 1);
            buf1[pos] = ((u64)(unsigned)d << 32) | pay;
        }
    }
}

// ---------------- bucket2: counting sort + code histogram, 1024 threads ----------------
__global__ __launch_bounds__(1024) void bucket2_kernel(const u64* __restrict__ buf1,
                                                       const int* __restrict__ btot,
                                                       int* __restrict__ row_start,
                                                       unsigned* __restrict__ edges,
                                                       unsigned* __restrict__ countsw,
                                                       int N, int bins) {
    __shared__ int cnt[256];
    __shared__ int cur[256];
    __shared__ int wts[4];
    __shared__ unsigned ccnt[256 * 18];
    __shared__ int sb[2];
    const int t = threadIdx.x, lane = t & 63, wid = t >> 6;
    const int bin = blockIdx.x;

    int v0 = 0, s0 = 0;
    if (t < 256) {
        v0 = (t < bins) ? btot[t] : 0;
        s0 = v0;
        #pragma unroll
        for (int off = 1; off < 64; off <<= 1) {
            int u = __shfl_up(s0, off, 64);
            if (lane >= off) s0 += u;
        }
        if (lane == 63) wts[wid] = s0;
        cnt[t] = 0;
    }
    for (int i = t; i < 256 * 18; i += 1024) ccnt[i] = 0;
    __syncthreads();
    if (t < 256) {
        int add = 0;
        #pragma unroll
        for (int w = 0; w < 4; ++w) add += (w < wid) ? wts[w] : 0;
        s0 += add;
        if (t == bin) { sb[0] = s0 - v0; sb[1] = s0; }   // lo, hi
    }
    __syncthreads();
    const int lo = sb[0], hi = sb[1];

    for (int i = lo + t; i < hi; i += 1024)
        atomicAdd(&cnt[(int)(buf1[i] >> 32) & 255], 1);
    __syncthreads();

    int v1 = 0, s1 = 0;
    if (t < 256) {
        v1 = cnt[t];
        s1 = v1;
        #pragma unroll
        for (int off = 1; off < 64; off <<= 1) {
            int u = __shfl_up(s1, off, 64);
            if (lane >= off) s1 += u;
        }
        if (lane == 63) wts[wid] = s1;
    }
    __syncthreads();
    if (t < 256) {
        int add = 0;
        #pragma unroll
        for (int w = 0; w < 4; ++w) add += (w < wid) ? wts[w] : 0;
        s1 += add;
        const int g = bin * 256 + t;
        if (g < N) row_start[g + 1] = lo + s1;
        cur[t] = s1 - v1;
        if (bin == 0 && t == 0) row_start[0] = 0;
    }
    __syncthreads();

    for (int i = lo + t; i < hi; i += 1024) {
        u64 rec = buf1[i];
        const int local = (int)(rec >> 32) & 255;
        int loc = atomicAdd(&cur[local], 1);
        edges[lo + loc] = (unsigned)rec;
        atomicAdd(&ccnt[local * 18 + ((unsigned)rec >> 16)], 1);
    }
    __syncthreads();

    if (t < 256) {
        const int g = bin * 256 + t;
        if (g < N) {
            unsigned w[5] = {0, 0, 0, 0, 0};
            #pragma unroll
            for (int c = 0; c < 18; ++c)
                w[c >> 2] |= ccnt[t * 18 + c] << (8 * (c & 3));
            #pragma unroll
            for (int k = 0; k < 5; ++k)
                countsw[(size_t)g * 5 + k] = w[k];
        }
    }
}

// ---------------- aggregation: persistent, one wave per node per iteration ----------------
__global__ __launch_bounds__(256) void aggregate_kernel(const u16* __restrict__ X,
                                                        const int* __restrict__ row_start,
                                                        const unsigned* __restrict__ edges,
                                                        const float* __restrict__ emb,
                                                        const unsigned* __restrict__ countsw,
                                                        u16* __restrict__ A, int N) {
    __shared__ float semb[18 * 128];
    for (int i = threadIdx.x; i < 18 * 128; i += 256) semb[i] = emb[i];
    __syncthreads();
    const int lane = threadIdx.x & 63;
    const int wstart = blockIdx.x * 4 + (threadIdx.x >> 6);
    const int wstride = gridDim.x * 4;
    const float2* sem2 = (const float2*)semb;

    for (int node = wstart; node < N; node += wstride) {
        unsigned cw[5];
        #pragma unroll
        for (int k = 0; k < 5; ++k) cw[k] = countsw[(size_t)node * 5 + k];

        int s = __builtin_amdgcn_readfirstlane(row_start[node]);
        const int e = __builtin_amdgcn_readfirstlane(row_start[node + 1]);
        float a0 = 0.f, a1 = 0.f;

        while (s < e) {
            const int take = (e - s < 64) ? (e - s) : 64;             // wave-uniform
            unsigned pl = edges[s + (lane < take ? lane : 0)];        // 1 coalesced load
            #pragma unroll
            for (int c = 0; c < 4; ++c) {
                const int cb = c * 16;
                if (cb < take) {                                      // uniform branch
                    unsigned ps[16];
                    unsigned xv[16];
                    #pragma unroll
                    for (int j = 0; j < 16; ++j)
                        ps[j] = __builtin_amdgcn_readlane(pl, cb + j);  // SGPR broadcast
                    #pragma unroll
                    for (int j = 0; j < 16; ++j)
                        xv[j] = *(const unsigned*)(X + (ps[j] & 0xFFFFu) * D_FEAT + lane * 2);
                    #pragma unroll
                    for (int j = 0; j < 16; ++j) {
                        const float m = (cb + j < take) ? 1.f : 0.f;  // uniform mask
                        a0 += m * __builtin_bit_cast(float, xv[j] << 16);
                        a1 += m * __builtin_bit_cast(float, xv[j] & 0xFFFF0000u);
                    }
                }
            }
            s += take;
        }

        #pragma unroll
        for (int w = 0; w < 5; ++w) {
            #pragma unroll
            for (int b = 0; b < 4; ++b) {
                const int code = w * 4 + b;
                if (code < 18) {
                    const float cf = (float)((cw[w] >> (8 * b)) & 255u);
                    float2 ev = sem2[code * 64 + lane];
                    a0 += cf * ev.x;
                    a1 += cf * ev.y;
                }
            }
        }

        unsigned outp = (unsigned)f2bf(a0) | ((unsigned)f2bf(a1) << 16);
        *(unsigned*)(A + (size_t)node * D_FEAT + lane * 2) = outp;
    }
}

// ---------------- MLP v2: register-resident weights, col-split waves ----------------
// Wave w owns GEMM1 cols [w*64, w*64+64) and GEMM2 cols [w*32, w*32+32).
// Per-wave weights: 16 + 16 frags = 128 VGPR, loaded once via b128 from frag-ordered
// F1/F2.  GEMM1: A-frags global b128, B in registers -> ZERO LDS.  Only h crosses
// waves: 32 KB XOR-swizzled LDS tile, one barrier.  Grid = nt one-tile blocks.
template <bool RELU2, bool OUTF32>
__global__ __launch_bounds__(256, 2) void mlp_kernel(const u16* __restrict__ A,
                                                     const u16* __restrict__ F1,
                                                     const float* __restrict__ bias1,
                                                     const u16* __restrict__ F2,
                                                     const float* __restrict__ bias2,
                                                     void* __restrict__ C, int M) {
    __shared__ __align__(16) u16 hh[64 * 256];   // 32 KB
    const int tid = threadIdx.x;
    const int w = tid >> 6;
    const int lane = tid & 63;
    const int m16 = lane & 15;
    const int quad = lane >> 4;
    const int row0 = blockIdx.x * 64;

    // A-frags for this tile (issue first: 16 independent global b128)
    s16x8 af[4][4];   // [rf][kb]
    #pragma unroll
    for (int rf = 0; rf < 4; ++rf) {
        const int arow = row0 + rf * 16 + m16;
        const bool ok = arow < M;
        #pragma unroll
        for (int kb = 0; kb < 4; ++kb)
            af[rf][kb] = ok ? *(const s16x8*)(A + (size_t)arow * 128 + kb * 32 + quad * 8)
                            : s16x8{};
    }

    // W1 slice: frags t = w*4+ct
    s16x8 b1f[4][4];  // [ct][kb]
    #pragma unroll
    for (int ct = 0; ct < 4; ++ct)
        #pragma unroll
        for (int kb = 0; kb < 4; ++kb)
            b1f[ct][kb] = *(const s16x8*)(F1 + (size_t)(((w * 4 + ct) * 4 + kb) * 64 + lane) * 8);

    float b1v[4];
    #pragma unroll
    for (int ct = 0; ct < 4; ++ct) b1v[ct] = bias1[(w * 4 + ct) * 16 + m16];

    // GEMM1: 64 rows x 64 cols, K=128 — all operands in registers
    f32x4 acc[4][4];  // [rf][ct]
    #pragma unroll
    for (int rf = 0; rf < 4; ++rf)
        #pragma unroll
        for (int ct = 0; ct < 4; ++ct) acc[rf][ct] = f32x4{0, 0, 0, 0};
    #pragma unroll
    for (int kb = 0; kb < 4; ++kb)
        #pragma unroll
        for (int rf = 0; rf < 4; ++rf)
            #pragma unroll
            for (int ct = 0; ct < 4; ++ct)
                acc[rf][ct] = __builtin_amdgcn_mfma_f32_16x16x32_bf16(af[rf][kb], b1f[ct][kb],
                                                                     acc[rf][ct], 0, 0, 0);

    // relu + bias -> hh (XOR-swizzled row-major [64][256])
    #pragma unroll
    for (int rf = 0; rf < 4; ++rf) {
        #pragma unroll
        for (int ct = 0; ct < 4; ++ct) {
            const int col = (w * 4 + ct) * 16 + m16;
            #pragma unroll
            for (int r = 0; r < 4; ++r) {
                const int lr = quad * 4 + r;          // row&7 == lr&7
                float v = acc[rf][ct][r] + b1v[ct];
                v = v > 0.f ? v : 0.f;
                hh[((rf * 16 + lr) * 256 + col) ^ ((lr & 7) << 3)] = f2bf(v);
            }
        }
    }

    // W2 slice loads (issue before barrier; used after)
    s16x8 b2f[2][8];  // [ct2][kb]
    #pragma unroll
    for (int ct2 = 0; ct2 < 2; ++ct2)
        #pragma unroll
        for (int kb = 0; kb < 8; ++kb)
            b2f[ct2][kb] = *(const s16x8*)(F2 + (size_t)(((w * 2 + ct2) * 8 + kb) * 64 + lane) * 8);
    float b2v[2];
    #pragma unroll
    for (int ct2 = 0; ct2 < 2; ++ct2) b2v[ct2] = bias2[(w * 2 + ct2) * 16 + m16];

    __syncthreads();

    // GEMM2: 64 rows x 32 cols, K=256 — A from hh, B in registers
    f32x4 acc2[4][2];
    #pragma unroll
    for (int rf = 0; rf < 4; ++rf)
        #pragma unroll
        for (int ct2 = 0; ct2 < 2; ++ct2) acc2[rf][ct2] = f32x4{0, 0, 0, 0};
    #pragma unroll
    for (int kb = 0; kb < 8; ++kb) {
        s16x8 haf[4];
        #pragma unroll
        for (int rf = 0; rf < 4; ++rf)
            haf[rf] = *(const s16x8*)(hh + (((rf * 16 + m16) * 256 + kb * 32 + quad * 8)
                                            ^ ((m16 & 7) << 3)));
        #pragma unroll
        for (int rf = 0; rf < 4; ++rf)
            #pragma unroll
            for (int ct2 = 0; ct2 < 2; ++ct2)
                acc2[rf][ct2] = __builtin_amdgcn_mfma_f32_16x16x32_bf16(haf[rf], b2f[ct2][kb],
                                                                       acc2[rf][ct2], 0, 0, 0);
    }

    // epilogue
    #pragma unroll
    for (int rf = 0; rf < 4; ++rf) {
        #pragma unroll
        for (int ct2 = 0; ct2 < 2; ++ct2) {
            const int col = (w * 2 + ct2) * 16 + m16;
            #pragma unroll
            for (int r = 0; r < 4; ++r) {
                const int row = row0 + rf * 16 + quad * 4 + r;
                if (row < M) {
                    float v = acc2[rf][ct2][r] + b2v[ct2];
                    if (RELU2) v = v > 0.f ? v : 0.f;
                    if (OUTF32) ((float*)C)[(size_t)row * 128 + col] = v;
                    else        ((u16*)C)[(size_t)row * 128 + col] = f2bf(v);
                }
            }
        }
    }
}

extern "C" void kernel_launch(void* const* d_in, const int* in_sizes, int n_in,
                              void* d_out, int out_size, void* d_ws, size_t ws_size,
                              hipStream_t stream) {
    const int N = in_sizes[0] / D_FEAT;     // 50000
    const int E = in_sizes[1] / 2;          // 800000

    const float* x    = (const float*)d_in[0];
    const int* eidx   = (const int*)d_in[1];
    const int* eattr  = (const int*)d_in[2];
    const float* ee1_0 = (const float*)d_in[3];
    const float* ee2_0 = (const float*)d_in[4];
    const float* W1_0  = (const float*)d_in[5];
    const float* b1_0  = (const float*)d_in[6];
    const float* W2_0  = (const float*)d_in[7];
    const float* b2_0  = (const float*)d_in[8];
    const float* ee1_1 = (const float*)d_in[9];
    const float* ee2_1 = (const float*)d_in[10];
    const float* W1_1  = (const float*)d_in[11];
    const float* b1_1  = (const float*)d_in[12];
    const float* W2_1  = (const float*)d_in[13];
    const float* b2_1  = (const float*)d_in[14];

    const int nb1  = (E + TILE1 - 1) / TILE1;     // 196
    const int bins = (N + 255) / 256;             // 196

    char* ws = (char*)d_ws;
    size_t off = 0;
    auto alloc = [&](size_t bytes) { size_t o = off; off = (off + bytes + 255) & ~(size_t)255; return o; };
    size_t o_rowstart = alloc((size_t)(N + 4) * 4);
    size_t o_edges    = alloc((size_t)E * 4);
    size_t o_ghist    = alloc((size_t)bins * nb1 * 4);
    size_t o_btot     = alloc((size_t)bins * 4);
    size_t o_counts   = alloc((size_t)N * 20);
    size_t o_emb      = alloc(2 * 18 * 128 * 4);
    size_t o_wt       = alloc(4 * 32768 * 2);
    size_t o_aa       = alloc((size_t)N * D_FEAT * 2);

    int*      row_start = (int*)(ws + o_rowstart);
    unsigned* edges     = (unsigned*)(ws + o_edges);
    int*      ghist     = (int*)(ws + o_ghist);
    int*      btot      = (int*)(ws + o_btot);
    unsigned* countsw   = (unsigned*)(ws + o_counts);
    float*    emb       = (float*)(ws + o_emb);
    u16*      F1_0      = (u16*)(ws + o_wt);
    u16*      F2_0      = F1_0 + 32768;
    u16*      F1_1      = F2_0 + 32768;
    u16*      F2_1      = F1_1 + 32768;
    u16*      AA        = (u16*)(ws + o_aa);
    u64*      buf1      = (u64*)(ws + o_aa);      // aliases AA (dead before aggregate)

    u16* X2 = (u16*)d_out;
    u16* xb = (u16*)d_out + (size_t)N * D_FEAT;

    const int nt = (N + 63) / 64;                 // 782
    const int n4 = N * D_FEAT / 4;
    const int nbA = 1024;                         // persistent tobf16 blocks
    const int aggB = 2048;                        // persistent aggregate blocks

    // 1) fused prep: tobf16 | hist1 | emb | frag-transpose
    prep_kernel<<<nbA + nb1 + 18 + 512, 256, 0, stream>>>(
        (const float4*)x, xb, n4, nbA,
        eidx + E, ghist, E, nb1, bins,
        ee1_0, ee2_0, ee1_1, ee2_1, emb,
        W1_0, W2_0, W1_1, W2_1, F1_0);

    // 2-4) CSR build
    scan1a_kernel<<<bins, 256, 0, stream>>>(ghist, btot, nb1);
    scatter1_kernel<<<nb1, 256, 0, stream>>>(eidx, eidx + E, eattr, ghist, btot, buf1, E, nb1, bins);
    bucket2_kernel<<<bins, 1024, 0, stream>>>(buf1, btot, row_start, edges, countsw, N, bins);

    // 5-6) layer 0
    aggregate_kernel<<<aggB, 256, 0, stream>>>(xb, row_start, edges, emb, countsw, AA, N);
    mlp_kernel<true, false><<<nt, 256, 0, stream>>>(AA, F1_0, b1_0, F2_0, b2_0, X2, N);

    // 7-8) layer 1
    aggregate_kernel<<<aggB, 256, 0, stream>>>(X2, row_start, edges, emb + 18 * 128, countsw, AA, N);
    mlp_kernel<false, true><<<nt, 256, 0, stream>>>(AA, F1_1, b1_1, F2_1, b2_1, d_out, N);
}